// Round 6
// baseline (773.901 us; speedup 1.0000x reference)
//
#include <hip/hip_runtime.h>

// RNNDecoderP round 6: WAVE SPECIALIZATION. 128-thread blocks, one block per
// (row,band). Wave 0 = layer-1 recurrence (3 shuffles + 1 LDS roundtrip on
// chain) + lag-2-chunk MLP head (off-chain filler). Wave 1 = layer-2 at
// lag-1-chunk (h1 inputs pre-produced -> off-chain; own chain = h2 roundtrip
// + 4 shuffles). Chunked double-buffered LDS rings (K=32), one s_barrier per
// chunk in BOTH branches (equal counts). Per-path regs ~130/150 -> no spill
// (rounds 2/4/5 showed >~200 live floats = scratch reloads on the chain).

typedef float v2f __attribute__((ext_vector_type(2)));

constexpr int Bn  = 256;
constexpr int Tn  = 2048;
constexpr int Dn  = 64;
constexpr int DBn = 32;
constexpr int Ln  = 2;
constexpr int Gn  = 96;
constexpr int Kc  = 32;      // steps per chunk

#if __has_builtin(__builtin_amdgcn_exp2f)
__device__ __forceinline__ float exp2_fast(float x) { return __builtin_amdgcn_exp2f(x); }
#else
__device__ __forceinline__ float exp2_fast(float x) { return exp2f(x); }
#endif
#if __has_builtin(__builtin_amdgcn_rcpf)
__device__ __forceinline__ float rcp_fast(float x) { return __builtin_amdgcn_rcpf(x); }
#else
__device__ __forceinline__ float rcp_fast(float x) { return 1.0f / x; }
#endif

__device__ __forceinline__ float sigmoid_f(float x) {
  return rcp_fast(1.0f + exp2_fast(-1.4426950408889634f * x));
}
__device__ __forceinline__ float tanh_f(float x) {
  return 1.0f - 2.0f * rcp_fast(1.0f + exp2_fast(2.8853900817779268f * x));
}

__device__ __forceinline__ float dot8(const v2f* __restrict__ w, const v2f* __restrict__ h) {
  v2f a = {0.0f, 0.0f};
  #pragma unroll
  for (int q = 0; q < 8; ++q) a = __builtin_elementwise_fma(w[q], h[q], a);
  return a.x + a.y;
}

__device__ __forceinline__ void ldlds(const float* p, v2f* d) {
  #pragma unroll
  for (int q = 0; q < 4; ++q) {
    float4 a = ((const float4*)p)[q];
    d[2*q] = (v2f){a.x, a.y}; d[2*q+1] = (v2f){a.z, a.w};
  }
}

__global__ __launch_bounds__(128, 1)
void rnn_decoder(const int* __restrict__ band_ids, const float* __restrict__ dtime,
                 const float* __restrict__ z_last, const float* __restrict__ projW,
                 const float* __restrict__ projB, const float* __restrict__ Wih,
                 const float* __restrict__ Whh, const float* __restrict__ bih,
                 const float* __restrict__ bhh, const float* __restrict__ mW1,
                 const float* __restrict__ mb1, const float* __restrict__ mW2,
                 const float* __restrict__ mb2, float* __restrict__ out) {
  const int b    = blockIdx.x >> 1;
  const int kb   = blockIdx.x & 1;
  const int tid  = threadIdx.x;        // 0..127
  const int w    = tid >> 6;           // wave id: 0 = L1+MLP, 1 = L2
  const int L    = tid & 63;           // lane in wave
  const int i    = L & 31;             // owned element index
  const int koff = (L >> 5) * 16;      // which 16-wide half of the dot

  __shared__ __align__(16) float yd[Tn + 1];          // compacted dtime -> outputs
  __shared__ __align__(16) float yc[2 * Tn];          // 2 MLP partials per step
  __shared__ __align__(16) float h1ring[2][Kc][DBn];  // wave0 -> wave1 (lag 1 chunk)
  __shared__ __align__(16) float h2ring[2][Kc][DBn];  // wave1 -> wave0 (lag 2 chunks)
  __shared__ __align__(16) float xb[DBn];
  __shared__ __align__(16) float xs[DBn];
  __shared__ int   nsh;
  __shared__ float y0sh;   // MLP(h2=0) raw sum (without mb2)

  const float mb2v = mb2[kb];

  // ================= setup (divergent by wave, joined by barrier A) =================
  // wave0 state
  float gb_r = 0, gb_z = 0, gb_n = 0, gs_r = 0, gs_z = 0, gs_n = 0;
  float bhh1n = 0, mb1i = 0, mW2i = 0;
  v2f w1r[8], w1z[8], w1n[8], m1p[8];
  // wave1 state
  float c2r = 0, c2z = 0, bih2n = 0, bhh2n = 0;
  v2f u2r[8], u2z[8], u2n[8], w2r[8], w2z[8], w2n[8];

  if (w == 0) {
    // -------- stable compaction of this band's dtime (64 lanes) --------
    const int*   brow = band_ids + b * Tn;
    const float* drow = dtime    + b * Tn;
    int cnt = 0;
    int4 bcache[8];
    #pragma unroll
    for (int it = 0; it < 8; ++it) {
      int4 v = ((const int4*)(brow + L * 32))[it];
      bcache[it] = v;
      cnt += (v.x == kb) + (v.y == kb) + (v.z == kb) + (v.w == kb);
    }
    int incl = cnt;
    #pragma unroll
    for (int dlt = 1; dlt < 64; dlt <<= 1) {
      int v = __shfl_up(incl, dlt, 64);
      if (L >= dlt) incl += v;
    }
    int off = incl - cnt;
    const int n0 = __shfl(incl, 63, 64);
    #pragma unroll
    for (int it = 0; it < 8; ++it) {
      int4   v  = bcache[it];
      float4 dd = ((const float4*)(drow + L * 32))[it];
      if (v.x == kb) yd[off++] = dd.x;
      if (v.y == kb) yd[off++] = dd.y;
      if (v.z == kb) yd[off++] = dd.z;
      if (v.w == kb) yd[off++] = dd.w;
    }
    if (L == 0) nsh = n0;

    // -------- projection fold: x_t = xb + d_t * xs --------
    {
      const float* pw = projW + (kb * (Dn + 1)) * DBn + i;
      const float* zl = z_last + b * Dn;
      float acc = 0.0f;
      #pragma unroll 8
      for (int k = 0; k < Dn; ++k) acc = fmaf(zl[k], pw[k * DBn], acc);
      xb[i] = acc + projB[kb * DBn + i];
      xs[i] = pw[Dn * DBn];
    }
    __builtin_amdgcn_wave_barrier();

    // -------- per-gate affine constants for layer-1 input --------
    const float* wih1  = Wih + ((kb * Ln + 0) * Gn) * DBn;
    const float* bih1p = bih + (kb * Ln + 0) * Gn;
    const float* bhh1p = bhh + (kb * Ln + 0) * Gn;
    #pragma unroll 4
    for (int j = 0; j < DBn; ++j) {
      float xbv = xb[j], xsv = xs[j];
      float wr = wih1[(     i) * DBn + j];
      float wz = wih1[(32 + i) * DBn + j];
      float wn = wih1[(64 + i) * DBn + j];
      gb_r = fmaf(wr, xbv, gb_r);  gs_r = fmaf(wr, xsv, gs_r);
      gb_z = fmaf(wz, xbv, gb_z);  gs_z = fmaf(wz, xsv, gs_z);
      gb_n = fmaf(wn, xbv, gb_n);  gs_n = fmaf(wn, xsv, gs_n);
    }
    gb_r += bih1p[i]      + bhh1p[i];
    gb_z += bih1p[32 + i] + bhh1p[32 + i];
    gb_n += bih1p[64 + i];
    bhh1n = bhh1p[64 + i];
    mb1i  = mb1[kb * DBn + i];
    mW2i  = mW2[kb * DBn + i];

    // -------- wave0 weights: Whh layer1 half-rows + mW1 half-column --------
    const float* whh1 = Whh + ((kb * Ln + 0) * Gn) * DBn;
    #pragma unroll
    for (int q = 0; q < 4; ++q) {
      float4 a;
      a = ((const float4*)(whh1 + (     i) * DBn + koff))[q];
      w1r[2*q] = (v2f){a.x, a.y}; w1r[2*q+1] = (v2f){a.z, a.w};
      a = ((const float4*)(whh1 + (32 + i) * DBn + koff))[q];
      w1z[2*q] = (v2f){a.x, a.y}; w1z[2*q+1] = (v2f){a.z, a.w};
      a = ((const float4*)(whh1 + (64 + i) * DBn + koff))[q];
      w1n[2*q] = (v2f){a.x, a.y}; w1n[2*q+1] = (v2f){a.z, a.w};
    }
    #pragma unroll
    for (int q = 0; q < 8; ++q)
      m1p[q] = (v2f){ mW1[(kb * DBn + koff + 2*q)     * DBn + i],
                      mW1[(kb * DBn + koff + 2*q + 1) * DBn + i] };

    // -------- y for h2 == 0 (n==0 fallback), raw 32-sum --------
    float c0 = fmaxf(mb1i, 0.0f) * mW2i;
    c0 += __shfl_xor(c0, 1, 64);
    c0 += __shfl_xor(c0, 2, 64);
    c0 += __shfl_xor(c0, 4, 64);
    c0 += __shfl_xor(c0, 8, 64);
    c0 += __shfl_xor(c0, 16, 64);
    if (L == 0) y0sh = c0;
  } else {
    // -------- wave1 weights: Wih/Whh layer2 half-rows + bias consts --------
    const float* wih2  = Wih + ((kb * Ln + 1) * Gn) * DBn;
    const float* whh2  = Whh + ((kb * Ln + 1) * Gn) * DBn;
    const float* bih2p = bih + (kb * Ln + 1) * Gn;
    const float* bhh2p = bhh + (kb * Ln + 1) * Gn;
    #pragma unroll
    for (int q = 0; q < 4; ++q) {
      float4 a;
      a = ((const float4*)(wih2 + (     i) * DBn + koff))[q];
      u2r[2*q] = (v2f){a.x, a.y}; u2r[2*q+1] = (v2f){a.z, a.w};
      a = ((const float4*)(wih2 + (32 + i) * DBn + koff))[q];
      u2z[2*q] = (v2f){a.x, a.y}; u2z[2*q+1] = (v2f){a.z, a.w};
      a = ((const float4*)(wih2 + (64 + i) * DBn + koff))[q];
      u2n[2*q] = (v2f){a.x, a.y}; u2n[2*q+1] = (v2f){a.z, a.w};
      a = ((const float4*)(whh2 + (     i) * DBn + koff))[q];
      w2r[2*q] = (v2f){a.x, a.y}; w2r[2*q+1] = (v2f){a.z, a.w};
      a = ((const float4*)(whh2 + (32 + i) * DBn + koff))[q];
      w2z[2*q] = (v2f){a.x, a.y}; w2z[2*q+1] = (v2f){a.z, a.w};
      a = ((const float4*)(whh2 + (64 + i) * DBn + koff))[q];
      w2n[2*q] = (v2f){a.x, a.y}; w2n[2*q+1] = (v2f){a.z, a.w};
    }
    c2r   = bih2p[i]      + bhh2p[i];
    c2z   = bih2p[32 + i] + bhh2p[32 + i];
    bih2n = bih2p[64 + i];
    bhh2n = bhh2p[64 + i];
  }
  __syncthreads();   // barrier A

  const int n = nsh;
  const int C = (n + Kc - 1) / Kc;   // chunks; C*Kc <= Tn

  // ================= main loop: equal s_barrier counts in both branches =================
  if (w == 0) {
    v2f h1a[8];
    #pragma unroll
    for (int q = 0; q < 8; ++q) h1a[q] = (v2f){0.0f, 0.0f};
    float h1self = 0.0f;
    for (int c = 0; c <= C + 1; ++c) {
      const bool doL1 = (c < C);
      const bool doML = (c >= 2);
      if (doL1 || doML) {
        float* h1w = &h1ring[c & 1][0][0];
        const float* h2r = &h2ring[c & 1][0][0];
        const int tL = c * Kc;
        const int tM = (c - 2) * Kc;
        for (int k = 0; k < Kc; ++k) {
          if (doL1) {
            // ---- layer-1 step tL+k (loop-carried chain) ----
            float d  = yd[tL + k];
            float ar = dot8(w1r, h1a);
            float az = dot8(w1z, h1a);
            float an = dot8(w1n, h1a);
            ar += __shfl_xor(ar, 32, 64);
            az += __shfl_xor(az, 32, 64);
            an += __shfl_xor(an, 32, 64);
            float r1 = sigmoid_f(fmaf(d, gs_r, gb_r) + ar);
            float z1 = sigmoid_f(fmaf(d, gs_z, gb_z) + az);
            float n1 = tanh_f(fmaf(d, gs_n, gb_n) + r1 * (an + bhh1n));
            h1self = fmaf(z1, h1self - n1, n1);
            h1w[k * DBn + i] = h1self;
            __builtin_amdgcn_wave_barrier();
          }
          if (doML) {
            // ---- MLP head for step tM+k (off-chain filler) ----
            v2f h2b[8];
            ldlds(&h2r[k * DBn + koff], h2b);
            float mh = dot8(m1p, h2b);
            mh += __shfl_xor(mh, 32, 64);
            float cc = fmaxf(mh + mb1i, 0.0f) * mW2i;
            cc += __shfl_xor(cc, 1, 64);
            cc += __shfl_xor(cc, 2, 64);
            cc += __shfl_xor(cc, 4, 64);
            cc += __shfl_xor(cc, 8, 64);
            const int t2 = tM + k;
            if (t2 < n && (L == 0 || L == 16)) yc[2 * t2 + (L >> 4)] = cc;
          }
          if (doL1) {
            ldlds(&h1w[k * DBn + koff], h1a);   // readback (latency covered by MLP)
          }
        }
      }
      __syncthreads();
    }
  } else {
    v2f h2a[8];
    #pragma unroll
    for (int q = 0; q < 8; ++q) h2a[q] = (v2f){0.0f, 0.0f};
    float h2self = 0.0f;
    for (int c = 0; c <= C + 1; ++c) {
      if (c >= 1 && c <= C) {
        const float* h1r = &h1ring[(c - 1) & 1][0][0];
        float* h2w = &h2ring[(c - 1) & 1][0][0];
        for (int k = 0; k < Kc; ++k) {
          // h1 input (pre-produced last chunk -> off the h2 chain)
          v2f h1b[8];
          ldlds(&h1r[k * DBn + koff], h1b);
          // recurrent dots (on-chain) + input dots (off-chain)
          float cr = dot8(w2r, h2a);
          float cz = dot8(w2z, h2a);
          float cn = dot8(w2n, h2a);
          float br = dot8(u2r, h1b);
          float bz = dot8(u2z, h1b);
          float bn = dot8(u2n, h1b);
          float sr = br + cr;  sr += __shfl_xor(sr, 32, 64);
          float sz = bz + cz;  sz += __shfl_xor(sz, 32, 64);
          bn += __shfl_xor(bn, 32, 64);
          cn += __shfl_xor(cn, 32, 64);
          float r2 = sigmoid_f(sr + c2r);
          float z2 = sigmoid_f(sz + c2z);
          float n2 = tanh_f(bn + bih2n + r2 * (cn + bhh2n));
          h2self = fmaf(z2, h2self - n2, n2);
          h2w[k * DBn + i] = h2self;
          __builtin_amdgcn_wave_barrier();
          ldlds(&h2w[k * DBn + koff], h2a);
        }
      }
      __syncthreads();
    }
  }

  // ================= joint epilogue =================
  for (int t = tid; t < n; t += 128) yd[t] = yc[2 * t] + yc[2 * t + 1] + mb2v;
  __syncthreads();
  const float ylast = (n >= 1) ? yd[n - 1] : (y0sh + mb2v);
  for (int t = n + tid; t < Tn; t += 128) yd[t] = ylast;
  __syncthreads();

  float* orow = out + (kb * Bn + b) * Tn;
  #pragma unroll
  for (int q = 0; q < 4; ++q) {
    const int idx = (q * 128 + tid) * 4;
    *(float4*)(orow + idx) = *(const float4*)&yd[idx];
  }
}

extern "C" void kernel_launch(void* const* d_in, const int* in_sizes, int n_in,
                              void* d_out, int out_size, void* d_ws, size_t ws_size,
                              hipStream_t stream) {
  const int*   band_ids = (const int*)  d_in[0];
  const float* dtime    = (const float*)d_in[1];
  const float* z_last   = (const float*)d_in[2];
  const float* projW    = (const float*)d_in[3];
  const float* projB    = (const float*)d_in[4];
  const float* Wih      = (const float*)d_in[5];
  const float* Whh      = (const float*)d_in[6];
  const float* bihp     = (const float*)d_in[7];
  const float* bhhp     = (const float*)d_in[8];
  const float* mW1      = (const float*)d_in[9];
  const float* mb1      = (const float*)d_in[10];
  const float* mW2      = (const float*)d_in[11];
  const float* mb2      = (const float*)d_in[12];
  float* out = (float*)d_out;
  rnn_decoder<<<dim3(Bn * 2), dim3(128), 0, stream>>>(
      band_ids, dtime, z_last, projW, projB, Wih, Whh, bihp, bhhp,
      mW1, mb1, mW2, mb2, out);
}

// Round 7
// 431.913 us; speedup vs baseline: 1.7918x; 1.7918x over previous
//
#include <hip/hip_runtime.h>

// RNNDecoderP round 7: 3-wave pipeline, DPP combines, zero shuffles on any chain.
// Lane mapping: partner = L^8 (same 16-lane DPP row). e = element bits{0,1,2,4,5},
// half = bit 3 -> half-dot (16 MACs) + one v_mov_dpp row_ror:8 add (pure VALU).
// w0: L1 recurrence (chain = 4x ds_read_b128 readback + dots + DPP + gates + 1 write).
// w1: gx2 = Wih2*h1 batch producer (lag-1 chunk, throughput-only) + y drain (lag-3).
// w2: L2 recurrence (gx2 from ring) + MLP hidden -> v partials (lag-2 chunk).
// Chunked double-buffered rings (Kc=32), one s_barrier per phase, equal counts.

typedef float v2f __attribute__((ext_vector_type(2)));

constexpr int Bn  = 256;
constexpr int Tn  = 2048;
constexpr int Dn  = 64;
constexpr int DBn = 32;
constexpr int Ln  = 2;
constexpr int Gn  = 96;
constexpr int Kc  = 32;     // steps per chunk/phase
constexpr int GXP = 100;    // padded gx2 row (96 gates)
constexpr int VP  = 36;     // padded v row (32 hiddens), 36%4==0 keeps b128 alignment

#if __has_builtin(__builtin_amdgcn_exp2f)
__device__ __forceinline__ float exp2_fast(float x) { return __builtin_amdgcn_exp2f(x); }
#else
__device__ __forceinline__ float exp2_fast(float x) { return exp2f(x); }
#endif
#if __has_builtin(__builtin_amdgcn_rcpf)
__device__ __forceinline__ float rcp_fast(float x) { return __builtin_amdgcn_rcpf(x); }
#else
__device__ __forceinline__ float rcp_fast(float x) { return 1.0f / x; }
#endif

__device__ __forceinline__ float sigmoid_f(float x) {
  return rcp_fast(1.0f + exp2_fast(-1.4426950408889634f * x));
}
__device__ __forceinline__ float tanh_f(float x) {
  return 1.0f - 2.0f * rcp_fast(1.0f + exp2_fast(2.8853900817779268f * x));
}

// xor-8 partner add via DPP row_ror:8 (ctrl 0x128; legal on CDNA, unlike row_bcast15)
__device__ __forceinline__ float dppx8_add(float x) {
  int y = __builtin_amdgcn_update_dpp(0, __builtin_bit_cast(int, x), 0x128, 0xf, 0xf, true);
  return x + __builtin_bit_cast(float, y);
}

// 16-float half-dot, single chain (off-chain work)
__device__ __forceinline__ float dot8(const v2f* __restrict__ w, const v2f* __restrict__ h) {
  v2f a = {0.0f, 0.0f};
  #pragma unroll
  for (int q = 0; q < 8; ++q) a = __builtin_elementwise_fma(w[q], h[q], a);
  return a.x + a.y;
}
// 16-float half-dot, two chains (on-chain work)
__device__ __forceinline__ float dot8b(const v2f* __restrict__ w, const v2f* __restrict__ h) {
  v2f a = {0.0f, 0.0f}, b = {0.0f, 0.0f};
  #pragma unroll
  for (int q = 0; q < 4; ++q) {
    a = __builtin_elementwise_fma(w[q], h[q], a);
    b = __builtin_elementwise_fma(w[q + 4], h[q + 4], b);
  }
  a = a + b;
  return a.x + a.y;
}

// load 16 consecutive floats (4 x float4) into v2f[8]
__device__ __forceinline__ void ld16(const float* p, v2f* d) {
  #pragma unroll
  for (int q = 0; q < 4; ++q) {
    float4 a = ((const float4*)p)[q];
    d[2*q] = (v2f){a.x, a.y}; d[2*q+1] = (v2f){a.z, a.w};
  }
}

__device__ __forceinline__ float sum32(const float* p) {
  const float4* vp = (const float4*)p;
  float4 A = vp[0], B = vp[1], C = vp[2], D = vp[3];
  float4 E = vp[4], F = vp[5], G = vp[6], H = vp[7];
  float s0 = ((A.x + A.y) + (A.z + A.w)) + ((B.x + B.y) + (B.z + B.w));
  float s1 = ((C.x + C.y) + (C.z + C.w)) + ((D.x + D.y) + (D.z + D.w));
  float s2 = ((E.x + E.y) + (E.z + E.w)) + ((F.x + F.y) + (F.z + F.w));
  float s3 = ((G.x + G.y) + (G.z + G.w)) + ((H.x + H.y) + (H.z + H.w));
  return (s0 + s1) + (s2 + s3);
}

__global__ __launch_bounds__(192, 1)
void rnn_decoder(const int* __restrict__ band_ids, const float* __restrict__ dtime,
                 const float* __restrict__ z_last, const float* __restrict__ projW,
                 const float* __restrict__ projB, const float* __restrict__ Wih,
                 const float* __restrict__ Whh, const float* __restrict__ bih,
                 const float* __restrict__ bhh, const float* __restrict__ mW1,
                 const float* __restrict__ mb1, const float* __restrict__ mW2,
                 const float* __restrict__ mb2, float* __restrict__ out) {
  const int b    = blockIdx.x >> 1;
  const int kb   = blockIdx.x & 1;
  const int tid  = threadIdx.x;              // 0..191
  const int w    = tid >> 6;                 // wave role
  const int L    = tid & 63;
  const int half = (L >> 3) & 1;             // K-half (bit 3 -> DPP partner L^8)
  const int e    = (L & 7) | ((L >> 4) << 3);// owned element/gate 0..31
  const int koff = half * 16;

  __shared__ __align__(16) float yd[Tn];              // compacted dtime -> y
  __shared__ __align__(16) float gxr_[2][Kc][GXP];    // w1 -> w2 input gates
  __shared__ __align__(16) float h1r_[2][Kc][DBn];    // w0 -> w1 hidden ring
  __shared__ __align__(16) float vr_[2][Kc][VP];      // w2 -> w1 scaled MLP hiddens
  __shared__ __align__(16) float h2sh[DBn];
  __shared__ __align__(16) float xb[DBn], xs[DBn];
  __shared__ int nsh;

  const float mb2v = mb2[kb];

  if (w == 0) {
    // ======== setup: compaction (uses L), proj fold, affine consts, Whh1 slices ========
    {
      const int*   brow = band_ids + b * Tn;
      const float* drow = dtime    + b * Tn;
      int cnt = 0;
      int4 bcache[8];
      #pragma unroll
      for (int it = 0; it < 8; ++it) {
        int4 v = ((const int4*)(brow + L * 32))[it];
        bcache[it] = v;
        cnt += (v.x == kb) + (v.y == kb) + (v.z == kb) + (v.w == kb);
      }
      int incl = cnt;
      #pragma unroll
      for (int dlt = 1; dlt < 64; dlt <<= 1) {
        int v = __shfl_up(incl, dlt, 64);
        if (L >= dlt) incl += v;
      }
      int off = incl - cnt;
      const int n0 = __shfl(incl, 63, 64);
      #pragma unroll
      for (int it = 0; it < 8; ++it) {
        int4   v  = bcache[it];
        float4 dd = ((const float4*)(drow + L * 32))[it];
        if (v.x == kb) yd[off++] = dd.x;
        if (v.y == kb) yd[off++] = dd.y;
        if (v.z == kb) yd[off++] = dd.z;
        if (v.w == kb) yd[off++] = dd.w;
      }
      if (L == 0) nsh = n0;
    }
    {
      const float* pw = projW + (kb * (Dn + 1)) * DBn + e;
      const float* zl = z_last + b * Dn;
      float acc = 0.0f;
      #pragma unroll 8
      for (int k = 0; k < Dn; ++k) acc = fmaf(zl[k], pw[k * DBn], acc);
      xb[e] = acc + projB[kb * DBn + e];   // partner lanes write identical values
      xs[e] = pw[Dn * DBn];
    }
    __builtin_amdgcn_wave_barrier();
    const float* wih1  = Wih + ((kb * Ln + 0) * Gn) * DBn;
    const float* bih1p = bih + (kb * Ln + 0) * Gn;
    const float* bhh1p = bhh + (kb * Ln + 0) * Gn;
    float gb_r = 0, gb_z = 0, gb_n = 0, gs_r = 0, gs_z = 0, gs_n = 0;
    #pragma unroll 4
    for (int j = 0; j < DBn; ++j) {
      float xbv = xb[j], xsv = xs[j];
      float wr = wih1[(     e) * DBn + j];
      float wz = wih1[(32 + e) * DBn + j];
      float wn = wih1[(64 + e) * DBn + j];
      gb_r = fmaf(wr, xbv, gb_r);  gs_r = fmaf(wr, xsv, gs_r);
      gb_z = fmaf(wz, xbv, gb_z);  gs_z = fmaf(wz, xsv, gs_z);
      gb_n = fmaf(wn, xbv, gb_n);  gs_n = fmaf(wn, xsv, gs_n);
    }
    gb_r += bih1p[e]      + bhh1p[e];
    gb_z += bih1p[32 + e] + bhh1p[32 + e];
    gb_n += bih1p[64 + e];
    const float bhh1n = bhh1p[64 + e];
    v2f w1r[8], w1z[8], w1n[8];
    const float* whh1 = Whh + ((kb * Ln + 0) * Gn) * DBn;
    ld16(whh1 + (     e) * DBn + koff, w1r);
    ld16(whh1 + (32 + e) * DBn + koff, w1z);
    ld16(whh1 + (64 + e) * DBn + koff, w1n);
    __syncthreads();   // barrier A

    const int n = nsh;
    const int C = (n + Kc - 1) >> 5;
    v2f h1a[8];
    #pragma unroll
    for (int q = 0; q < 8; ++q) h1a[q] = (v2f){0.0f, 0.0f};
    float h1self = 0.0f;
    for (int c = 0; c < C + 3; ++c) {
      if (c < C) {
        float* ring = &h1r_[c & 1][0][0];
        const int t0 = c * Kc;
        for (int k = 0; k < Kc; ++k) {
          float d  = yd[t0 + k];
          float ar = dot8b(w1r, h1a);
          float az = dot8b(w1z, h1a);
          float an = dot8b(w1n, h1a);
          ar = dppx8_add(ar);                 // pure-VALU cross-half combine
          az = dppx8_add(az);
          an = dppx8_add(an);
          float r1 = sigmoid_f(fmaf(d, gs_r, gb_r) + ar);
          float z1 = sigmoid_f(fmaf(d, gs_z, gb_z) + az);
          float n1 = tanh_f(fmaf(d, gs_n, gb_n) + r1 * (an + bhh1n));
          h1self = fmaf(z1, h1self - n1, n1);
          ring[k * DBn + e] = h1self;         // partner writes identical value
          __builtin_amdgcn_wave_barrier();
          ld16(&ring[k * DBn + koff], h1a);   // only dependent DS stage on chain
        }
      }
      __syncthreads();
    }
  } else if (w == 1) {
    // ======== setup: Wih2 half-rows for gates e, 32+e, 64+e ========
    const float* wih2 = Wih + ((kb * Ln + 1) * Gn) * DBn;
    v2f wa[8], wbv[8], wcv[8];
    ld16(wih2 + (     e) * DBn + koff, wa);
    ld16(wih2 + (32 + e) * DBn + koff, wbv);
    ld16(wih2 + (64 + e) * DBn + koff, wcv);
    __syncthreads();   // barrier A

    const int n = nsh;
    const int C = (n + Kc - 1) >> 5;
    for (int c = 0; c < C + 3; ++c) {
      if (c >= 1 && c <= C) {
        const int cp = c - 1;
        const float* hsrc = &h1r_[cp & 1][0][0];
        float* gxo = &gxr_[cp & 1][0][0];
        for (int k = 0; k < Kc; ++k) {
          v2f hb[8];
          ld16(&hsrc[k * DBn + koff], hb);
          float g0 = dot8(wa,  hb);
          float g1 = dot8(wbv, hb);
          float g2 = dot8(wcv, hb);
          g0 = dppx8_add(g0);
          g1 = dppx8_add(g1);
          g2 = dppx8_add(g2);
          gxo[k * GXP +      e] = g0;
          gxo[k * GXP + 32 + e] = g1;
          gxo[k * GXP + 64 + e] = g2;
        }
      }
      if (c >= 3 && (c - 3) < C) {
        const int cd = c - 3;                 // drain y for chunk cd
        const float* vv = &vr_[cd & 1][0][0];
        if (L < 32) {
          float s = sum32(&vv[L * VP]);
          yd[cd * Kc + L] = s + mb2v;
        }
      }
      __syncthreads();
    }
  } else {
    // ======== setup: Whh2 half-rows, mW1 half-column, biases ========
    const float* whh2  = Whh + ((kb * Ln + 1) * Gn) * DBn;
    const float* bih2p = bih + (kb * Ln + 1) * Gn;
    const float* bhh2p = bhh + (kb * Ln + 1) * Gn;
    v2f r2w[8], z2w[8], n2w[8], m1c[8];
    ld16(whh2 + (     e) * DBn + koff, r2w);
    ld16(whh2 + (32 + e) * DBn + koff, z2w);
    ld16(whh2 + (64 + e) * DBn + koff, n2w);
    #pragma unroll
    for (int q = 0; q < 8; ++q)
      m1c[q] = (v2f){ mW1[(kb * DBn + koff + 2*q)     * DBn + e],
                      mW1[(kb * DBn + koff + 2*q + 1) * DBn + e] };
    const float c2r   = bih2p[e]      + bhh2p[e];
    const float c2z   = bih2p[32 + e] + bhh2p[32 + e];
    const float bih2n = bih2p[64 + e];
    const float bhh2n = bhh2p[64 + e];
    const float mb1e  = mb1[kb * DBn + e];
    const float mW2e  = mW2[kb * DBn + e];
    vr_[0][0][e] = fmaxf(mb1e, 0.0f) * mW2e;   // n==0 fallback (only read when C==0)
    __syncthreads();   // barrier A

    const int n = nsh;
    const int C = (n + Kc - 1) >> 5;
    v2f h2a[8];
    #pragma unroll
    for (int q = 0; q < 8; ++q) h2a[q] = (v2f){0.0f, 0.0f};
    float h2self = 0.0f;
    for (int c = 0; c < C + 3; ++c) {
      if (c >= 2 && c <= C + 1) {
        const int cc = c - 2;
        const float* gx = &gxr_[cc & 1][0][0];
        float* vo = &vr_[cc & 1][0][0];
        for (int k = 0; k < Kc; ++k) {
          float gxr = gx[k * GXP +      e];   // pre-produced -> off-chain reads
          float gxz = gx[k * GXP + 32 + e];
          float gxn = gx[k * GXP + 64 + e];
          float cr = dot8b(r2w, h2a);
          float cz = dot8b(z2w, h2a);
          float cn = dot8b(n2w, h2a);
          cr = dppx8_add(cr);
          cz = dppx8_add(cz);
          cn = dppx8_add(cn);
          float r2v = sigmoid_f(gxr + cr + c2r);
          float z2v = sigmoid_f(gxz + cz + c2z);
          float n2v = tanh_f(gxn + bih2n + r2v * (cn + bhh2n));
          h2self = fmaf(z2v, h2self - n2v, n2v);
          h2sh[e] = h2self;
          __builtin_amdgcn_wave_barrier();
          ld16(&h2sh[koff], h2a);
          // MLP hidden for this step (off-chain): v[k][e] = relu(h2 . mW1[:,e] + mb1)*mW2
          float mh = dot8(m1c, h2a);
          mh = dppx8_add(mh);
          vo[k * VP + e] = fmaxf(mh + mb1e, 0.0f) * mW2e;
        }
      }
      __syncthreads();
    }
  }

  // ================= joint epilogue =================
  const int n = nsh;
  float ylast;
  if (n > 0) {
    ylast = yd[n - 1];
  } else {
    ylast = sum32(&vr_[0][0][0]) + mb2v;
  }
  for (int t = n + tid; t < Tn; t += 192) yd[t] = ylast;
  __syncthreads();

  float* orow = out + (kb * Bn + b) * Tn;
  for (int q = tid; q < Tn / 4; q += 192)
    ((float4*)orow)[q] = ((const float4*)yd)[q];
}

extern "C" void kernel_launch(void* const* d_in, const int* in_sizes, int n_in,
                              void* d_out, int out_size, void* d_ws, size_t ws_size,
                              hipStream_t stream) {
  const int*   band_ids = (const int*)  d_in[0];
  const float* dtime    = (const float*)d_in[1];
  const float* z_last   = (const float*)d_in[2];
  const float* projW    = (const float*)d_in[3];
  const float* projB    = (const float*)d_in[4];
  const float* Wih      = (const float*)d_in[5];
  const float* Whh      = (const float*)d_in[6];
  const float* bihp     = (const float*)d_in[7];
  const float* bhhp     = (const float*)d_in[8];
  const float* mW1      = (const float*)d_in[9];
  const float* mb1      = (const float*)d_in[10];
  const float* mW2      = (const float*)d_in[11];
  const float* mb2      = (const float*)d_in[12];
  float* out = (float*)d_out;
  rnn_decoder<<<dim3(Bn * 2), dim3(192), 0, stream>>>(
      band_ids, dtime, z_last, projW, projB, Wih, Whh, bihp, bhhp,
      mW1, mb1, mW2, mb2, out);
}

// Round 8
// 325.482 us; speedup vs baseline: 2.3777x; 1.3270x over previous
//
#include <hip/hip_runtime.h>

// RNNDecoderP round 8: 4-wave pipeline, slim DS, MLP off the L2 chain.
// w0: L1 recurrence (chunk c).      chain: dots -> gates -> ds_write -> ld16
// w1: gx2 = Wih2*h1 (chunk c-1), packed float4 write; + y drain (chunk c-4)
// w2: L2 recurrence (chunk c-2).    chain like w0; gx read = ONE b128
// w3: MLP head (chunk c-3): ld16 h2ring, dot, DPP ror-reduce -> 4 partials
// v-partials: full 16-lane in-register sum via row_ror 8/4/2/1 (pure VALU);
// drain = 1 b128 + 1 b32 per 32 steps (was 8 b128/lane). s_setprio(1) on the
// recurrence waves. Wall time == per-step chain latency of slowest wave.

typedef float v2f __attribute__((ext_vector_type(2)));

constexpr int Bn  = 256;
constexpr int Tn  = 2048;
constexpr int Dn  = 64;
constexpr int DBn = 32;
constexpr int Ln  = 2;
constexpr int Gn  = 96;
constexpr int Kc  = 32;     // steps per chunk/phase

#if __has_builtin(__builtin_amdgcn_exp2f)
__device__ __forceinline__ float exp2_fast(float x) { return __builtin_amdgcn_exp2f(x); }
#else
__device__ __forceinline__ float exp2_fast(float x) { return exp2f(x); }
#endif
#if __has_builtin(__builtin_amdgcn_rcpf)
__device__ __forceinline__ float rcp_fast(float x) { return __builtin_amdgcn_rcpf(x); }
#else
__device__ __forceinline__ float rcp_fast(float x) { return 1.0f / x; }
#endif

__device__ __forceinline__ float sigmoid_f(float x) {
  return rcp_fast(1.0f + exp2_fast(-1.4426950408889634f * x));
}
__device__ __forceinline__ float tanh_f(float x) {
  return 1.0f - 2.0f * rcp_fast(1.0f + exp2_fast(2.8853900817779268f * x));
}

template <int CTRL>
__device__ __forceinline__ float dpp_add(float x) {
  int y = __builtin_amdgcn_update_dpp(0, __builtin_bit_cast(int, x), CTRL, 0xf, 0xf, true);
  return x + __builtin_bit_cast(float, y);
}
// cross-half (L^8) combine: row_ror:8
__device__ __forceinline__ float dppx8_add(float x) { return dpp_add<0x128>(x); }
// full 16-lane row sum, result in ALL lanes: ror8+ror4+ror2+ror1 circulant reduce
__device__ __forceinline__ float dpp_row_sum16(float x) {
  x = dpp_add<0x128>(x);
  x = dpp_add<0x124>(x);
  x = dpp_add<0x122>(x);
  x = dpp_add<0x121>(x);
  return x;
}

// 16-float half-dot, single chain (off-chain work)
__device__ __forceinline__ float dot8(const v2f* __restrict__ w, const v2f* __restrict__ h) {
  v2f a = {0.0f, 0.0f};
  #pragma unroll
  for (int q = 0; q < 8; ++q) a = __builtin_elementwise_fma(w[q], h[q], a);
  return a.x + a.y;
}
// 16-float half-dot, two chains (on-chain work)
__device__ __forceinline__ float dot8b(const v2f* __restrict__ w, const v2f* __restrict__ h) {
  v2f a = {0.0f, 0.0f}, b = {0.0f, 0.0f};
  #pragma unroll
  for (int q = 0; q < 4; ++q) {
    a = __builtin_elementwise_fma(w[q], h[q], a);
    b = __builtin_elementwise_fma(w[q + 4], h[q + 4], b);
  }
  a = a + b;
  return a.x + a.y;
}

// load 16 consecutive floats (4 x float4) into v2f[8]
__device__ __forceinline__ void ld16(const float* p, v2f* d) {
  #pragma unroll
  for (int q = 0; q < 4; ++q) {
    float4 a = ((const float4*)p)[q];
    d[2*q] = (v2f){a.x, a.y}; d[2*q+1] = (v2f){a.z, a.w};
  }
}

__global__ __launch_bounds__(256, 1)
void rnn_decoder(const int* __restrict__ band_ids, const float* __restrict__ dtime,
                 const float* __restrict__ z_last, const float* __restrict__ projW,
                 const float* __restrict__ projB, const float* __restrict__ Wih,
                 const float* __restrict__ Whh, const float* __restrict__ bih,
                 const float* __restrict__ bhh, const float* __restrict__ mW1,
                 const float* __restrict__ mb1, const float* __restrict__ mW2,
                 const float* __restrict__ mb2, float* __restrict__ out) {
  const int b    = blockIdx.x >> 1;
  const int kb   = blockIdx.x & 1;
  const int tid  = threadIdx.x;              // 0..255
  const int w    = tid >> 6;                 // wave role
  const int L    = tid & 63;
  const int e    = (L & 7) | ((L >> 4) << 3);// owned element/gate 0..31
  const int koff = ((L >> 3) & 1) * 16;      // K-half (bit 3 -> DPP partner L^8)

  __shared__ __align__(16) float yd[Tn];               // compacted dtime -> y
  __shared__ __align__(16) float gxr_[2][Kc][DBn][4];  // w1 -> w2 packed gates
  __shared__ __align__(16) float h1r_[2][Kc][DBn];     // w0 -> w1 ring
  __shared__ __align__(16) float h2r_[2][Kc][DBn];     // w2 -> w3 ring (+ own readback)
  __shared__ __align__(16) float vr_[2][Kc][4];        // w3 -> w1 y-partials
  __shared__ __align__(16) float xb[DBn], xs[DBn];
  __shared__ int nsh;

  const float mb2v = mb2[kb];

  if (w == 0) {
    // ======== setup: compaction, proj fold, affine consts, Whh1 slices ========
    {
      const int*   brow = band_ids + b * Tn;
      const float* drow = dtime    + b * Tn;
      int cnt = 0;
      int4 bcache[8];
      #pragma unroll
      for (int it = 0; it < 8; ++it) {
        int4 v = ((const int4*)(brow + L * 32))[it];
        bcache[it] = v;
        cnt += (v.x == kb) + (v.y == kb) + (v.z == kb) + (v.w == kb);
      }
      int incl = cnt;
      #pragma unroll
      for (int dlt = 1; dlt < 64; dlt <<= 1) {
        int v = __shfl_up(incl, dlt, 64);
        if (L >= dlt) incl += v;
      }
      int off = incl - cnt;
      const int n0 = __shfl(incl, 63, 64);
      #pragma unroll
      for (int it = 0; it < 8; ++it) {
        int4   v  = bcache[it];
        float4 dd = ((const float4*)(drow + L * 32))[it];
        if (v.x == kb) yd[off++] = dd.x;
        if (v.y == kb) yd[off++] = dd.y;
        if (v.z == kb) yd[off++] = dd.z;
        if (v.w == kb) yd[off++] = dd.w;
      }
      if (L == 0) nsh = n0;
    }
    {
      const float* pw = projW + (kb * (Dn + 1)) * DBn + e;
      const float* zl = z_last + b * Dn;
      float acc = 0.0f;
      #pragma unroll 8
      for (int k = 0; k < Dn; ++k) acc = fmaf(zl[k], pw[k * DBn], acc);
      xb[e] = acc + projB[kb * DBn + e];   // partner lanes write identical values
      xs[e] = pw[Dn * DBn];
    }
    __builtin_amdgcn_wave_barrier();
    const float* wih1  = Wih + ((kb * Ln + 0) * Gn) * DBn;
    const float* bih1p = bih + (kb * Ln + 0) * Gn;
    const float* bhh1p = bhh + (kb * Ln + 0) * Gn;
    float gb_r = 0, gb_z = 0, gb_n = 0, gs_r = 0, gs_z = 0, gs_n = 0;
    #pragma unroll 4
    for (int j = 0; j < DBn; ++j) {
      float xbv = xb[j], xsv = xs[j];
      float wr = wih1[(     e) * DBn + j];
      float wz = wih1[(32 + e) * DBn + j];
      float wn = wih1[(64 + e) * DBn + j];
      gb_r = fmaf(wr, xbv, gb_r);  gs_r = fmaf(wr, xsv, gs_r);
      gb_z = fmaf(wz, xbv, gb_z);  gs_z = fmaf(wz, xsv, gs_z);
      gb_n = fmaf(wn, xbv, gb_n);  gs_n = fmaf(wn, xsv, gs_n);
    }
    gb_r += bih1p[e]      + bhh1p[e];
    gb_z += bih1p[32 + e] + bhh1p[32 + e];
    gb_n += bih1p[64 + e];
    const float bhh1n = bhh1p[64 + e];
    v2f w1r[8], w1z[8], w1n[8];
    const float* whh1 = Whh + ((kb * Ln + 0) * Gn) * DBn;
    ld16(whh1 + (     e) * DBn + koff, w1r);
    ld16(whh1 + (32 + e) * DBn + koff, w1z);
    ld16(whh1 + (64 + e) * DBn + koff, w1n);
    __syncthreads();   // barrier A

#if __has_builtin(__builtin_amdgcn_s_setprio)
    __builtin_amdgcn_s_setprio(1);   // recurrence wave: win issue arbitration
#endif
    const int n = nsh;
    const int C = (n + Kc - 1) >> 5;
    v2f h1a[8];
    #pragma unroll
    for (int q = 0; q < 8; ++q) h1a[q] = (v2f){0.0f, 0.0f};
    float h1self = 0.0f;
    for (int c = 0; c < C + 4; ++c) {
      if (c < C) {
        float* ring = &h1r_[c & 1][0][0];
        const int t0 = c * Kc;
        for (int k = 0; k < Kc; ++k) {
          float d  = yd[t0 + k];
          float ar = dot8b(w1r, h1a);
          float az = dot8b(w1z, h1a);
          float an = dot8b(w1n, h1a);
          ar = dppx8_add(ar);
          az = dppx8_add(az);
          an = dppx8_add(an);
          float r1 = sigmoid_f(fmaf(d, gs_r, gb_r) + ar);
          float z1 = sigmoid_f(fmaf(d, gs_z, gb_z) + az);
          float n1 = tanh_f(fmaf(d, gs_n, gb_n) + r1 * (an + bhh1n));
          h1self = fmaf(z1, h1self - n1, n1);
          ring[k * DBn + e] = h1self;
          __builtin_amdgcn_wave_barrier();
          ld16(&ring[k * DBn + koff], h1a);   // the only dependent DS stage
        }
      }
      __syncthreads();
    }
  } else if (w == 1) {
    // ======== setup: Wih2 half-rows ========
    const float* wih2 = Wih + ((kb * Ln + 1) * Gn) * DBn;
    v2f wa[8], wbv[8], wcv[8];
    ld16(wih2 + (     e) * DBn + koff, wa);
    ld16(wih2 + (32 + e) * DBn + koff, wbv);
    ld16(wih2 + (64 + e) * DBn + koff, wcv);
    __syncthreads();   // barrier A

    const int n = nsh;
    const int C = (n + Kc - 1) >> 5;
    for (int c = 0; c < C + 4; ++c) {
      if (c >= 1 && c <= C) {
        const int cp = c - 1;
        const float* hsrc = &h1r_[cp & 1][0][0];
        for (int k = 0; k < Kc; ++k) {
          v2f hb[8];
          ld16(&hsrc[k * DBn + koff], hb);
          float g0 = dot8(wa,  hb);
          float g1 = dot8(wbv, hb);
          float g2 = dot8(wcv, hb);
          g0 = dppx8_add(g0);
          g1 = dppx8_add(g1);
          g2 = dppx8_add(g2);
          float4 gv; gv.x = g0; gv.y = g1; gv.z = g2; gv.w = 0.0f;
          *(float4*)&gxr_[cp & 1][k][e][0] = gv;   // 2-way same-addr write (free)
        }
      }
      if (c >= 4) {
        const int cd = c - 4;                      // drain y for chunk cd
        if (cd < C && L < 32) {
          float4 p = *(const float4*)&vr_[cd & 1][L][0];
          yd[cd * Kc + L] = ((p.x + p.y) + (p.z + p.w)) + mb2v;
        }
      }
      __syncthreads();
    }
  } else if (w == 2) {
    // ======== setup: Whh2 half-rows + bias consts ========
    const float* whh2  = Whh + ((kb * Ln + 1) * Gn) * DBn;
    const float* bih2p = bih + (kb * Ln + 1) * Gn;
    const float* bhh2p = bhh + (kb * Ln + 1) * Gn;
    v2f r2w[8], z2w[8], n2w[8];
    ld16(whh2 + (     e) * DBn + koff, r2w);
    ld16(whh2 + (32 + e) * DBn + koff, z2w);
    ld16(whh2 + (64 + e) * DBn + koff, n2w);
    const float c2r   = bih2p[e]      + bhh2p[e];
    const float c2z   = bih2p[32 + e] + bhh2p[32 + e];
    const float bih2n = bih2p[64 + e];
    const float bhh2n = bhh2p[64 + e];
    __syncthreads();   // barrier A

#if __has_builtin(__builtin_amdgcn_s_setprio)
    __builtin_amdgcn_s_setprio(1);   // recurrence wave
#endif
    const int n = nsh;
    const int C = (n + Kc - 1) >> 5;
    v2f h2a[8];
    #pragma unroll
    for (int q = 0; q < 8; ++q) h2a[q] = (v2f){0.0f, 0.0f};
    float h2self = 0.0f;
    for (int c = 0; c < C + 4; ++c) {
      if (c >= 2 && c <= C + 1) {
        const int cc = c - 2;
        float* ring = &h2r_[cc & 1][0][0];
        for (int k = 0; k < Kc; ++k) {
          float4 g = *(const float4*)&gxr_[cc & 1][k][e][0];  // one b128, pre-produced
          float cr = dot8b(r2w, h2a);
          float cz = dot8b(z2w, h2a);
          float cn = dot8b(n2w, h2a);
          cr = dppx8_add(cr);
          cz = dppx8_add(cz);
          cn = dppx8_add(cn);
          float r2v = sigmoid_f(g.x + cr + c2r);
          float z2v = sigmoid_f(g.y + cz + c2z);
          float n2v = tanh_f(g.z + bih2n + r2v * (cn + bhh2n));
          h2self = fmaf(z2v, h2self - n2v, n2v);
          ring[k * DBn + e] = h2self;
          __builtin_amdgcn_wave_barrier();
          ld16(&ring[k * DBn + koff], h2a);   // chain ends here; no MLP tail
        }
      }
      __syncthreads();
    }
  } else {
    // ======== setup: mW1 half-column, mb1, mW2 (pre-scaled 0.5 for dual-count) ========
    v2f m1c[8];
    #pragma unroll
    for (int q = 0; q < 8; ++q)
      m1c[q] = (v2f){ mW1[(kb * DBn + koff + 2*q)     * DBn + e],
                      mW1[(kb * DBn + koff + 2*q + 1) * DBn + e] };
    const float mb1e = mb1[kb * DBn + e];
    const float mW2h = 0.5f * mW2[kb * DBn + e];
    // n==0 fallback partials (only consumed when C==0)
    {
      float p = fmaxf(mb1e, 0.0f) * mW2h;
      p = dpp_row_sum16(p);
      if ((L & 15) == 15) vr_[0][L >> 4][(L >> 4) & 3] = p;  // placeholder, fixed below
    }
    // correct fallback slot: vr_[0][0][row]
    {
      float p = fmaxf(mb1e, 0.0f) * mW2h;
      p = dpp_row_sum16(p);
      if ((L & 15) == 15) vr_[0][0][L >> 4] = p;
    }
    __syncthreads();   // barrier A

    const int n = nsh;
    const int C = (n + Kc - 1) >> 5;
    for (int c = 0; c < C + 4; ++c) {
      if (c >= 3 && c <= C + 2) {
        const int cm = c - 3;
        const float* hsrc = &h2r_[cm & 1][0][0];
        for (int k = 0; k < Kc; ++k) {
          v2f hb[8];
          ld16(&hsrc[k * DBn + koff], hb);
          float mh = dot8(m1c, hb);
          mh = dppx8_add(mh);
          float v = fmaxf(mh + mb1e, 0.0f) * mW2h;
          v = dpp_row_sum16(v);                    // pure-VALU 16-lane reduce
          if ((L & 15) == 15) vr_[cm & 1][k][L >> 4] = v;
        }
      }
      __syncthreads();
    }
  }

  // ================= joint epilogue =================
  const int n = nsh;
  float ylast;
  if (n > 0) {
    ylast = yd[n - 1];
  } else {
    float4 p = *(const float4*)&vr_[0][0][0];
    ylast = ((p.x + p.y) + (p.z + p.w)) + mb2v;
  }
  for (int t = n + tid; t < Tn; t += 256) yd[t] = ylast;
  __syncthreads();

  float* orow = out + (kb * Bn + b) * Tn;
  for (int q = tid; q < Tn / 4; q += 256)
    ((float4*)orow)[q] = ((const float4*)yd)[q];
}

extern "C" void kernel_launch(void* const* d_in, const int* in_sizes, int n_in,
                              void* d_out, int out_size, void* d_ws, size_t ws_size,
                              hipStream_t stream) {
  const int*   band_ids = (const int*)  d_in[0];
  const float* dtime    = (const float*)d_in[1];
  const float* z_last   = (const float*)d_in[2];
  const float* projW    = (const float*)d_in[3];
  const float* projB    = (const float*)d_in[4];
  const float* Wih      = (const float*)d_in[5];
  const float* Whh      = (const float*)d_in[6];
  const float* bihp     = (const float*)d_in[7];
  const float* bhhp     = (const float*)d_in[8];
  const float* mW1      = (const float*)d_in[9];
  const float* mb1      = (const float*)d_in[10];
  const float* mW2      = (const float*)d_in[11];
  const float* mb2      = (const float*)d_in[12];
  float* out = (float*)d_out;
  rnn_decoder<<<dim3(Bn * 2), dim3(256), 0, stream>>>(
      band_ids, dtime, z_last, projW, projB, Wih, Whh, bihp, bhhp,
      mW1, mb1, mW2, mb2, out);
}